// Round 3
// baseline (22347.708 us; speedup 1.0000x reference)
//
#include <hip/hip_runtime.h>
#include <math.h>

// Shapes (fixed by reference)
#define BB 4
#define CC 64
#define HH 96
#define WW 96

static inline int ceil_div(long a, long b) { return (int)((a + b - 1) / b); }

// ---------------- bilinear 4x upsample (half-pixel centers, edge clamp) ----------------
__global__ void k_bilinear4x(const float* __restrict__ in, float* __restrict__ out,
                             int B, int C, int Hin, int Win) {
    int Hout = Hin * 4, Wout = Win * 4;
    long total = (long)B * C * Hout * Wout;
    long idx = blockIdx.x * (long)blockDim.x + threadIdx.x;
    if (idx >= total) return;
    int x = idx % Wout; long r = idx / Wout;
    int y = r % Hout; r /= Hout;
    int c = r % C; int b = (int)(r / C);
    float sy = 0.25f * (y + 0.5f) - 0.5f;
    float sx = 0.25f * (x + 0.5f) - 0.5f;
    int iy0 = (int)floorf(sy); float fy = sy - iy0;
    int ix0 = (int)floorf(sx); float fx = sx - ix0;
    int iy1 = iy0 + 1, ix1 = ix0 + 1;
    iy0 = min(max(iy0, 0), Hin - 1); iy1 = min(max(iy1, 0), Hin - 1);
    ix0 = min(max(ix0, 0), Win - 1); ix1 = min(max(ix1, 0), Win - 1);
    const float* p = in + ((long)(b * C + c) * Hin) * Win;
    float v = (1.f - fy) * ((1.f - fx) * p[iy0 * Win + ix0] + fx * p[iy0 * Win + ix1])
            +        fy  * ((1.f - fx) * p[iy1 * Win + ix0] + fx * p[iy1 * Win + ix1]);
    out[idx] = v;
}

// ---------------- generic 3x3 conv, pad 1, 2x2 spatial micro-tile per thread ----------------
// shuffle: 0 = normal write; 1 = pixel_shuffle(r=2) fused into the store.
// addsrc: optional residual added (same [B,Cout,H,W] layout), nullable.
__global__ void k_conv3(const float* __restrict__ in, const float* __restrict__ w,
                        const float* __restrict__ bias, const float* __restrict__ addsrc,
                        float* __restrict__ out,
                        int B, int Cin, int Cout, int H, int W, int relu, int shuffle) {
    int W2 = W >> 1, H2 = H >> 1;
    long total = (long)B * Cout * H2 * W2;
    long idx = blockIdx.x * (long)blockDim.x + threadIdx.x;
    if (idx >= total) return;
    int tx = idx % W2; long r = idx / W2;
    int ty = r % H2; r /= H2;
    int co = r % Cout; int b = (int)(r / Cout);
    int x0 = tx * 2, y0 = ty * 2;

    float a00, a01, a10, a11;
    float bv = bias[co];
    a00 = a01 = a10 = a11 = bv;

    const float* wp = w + (long)co * Cin * 9;
    const float* ip = in + (long)b * Cin * H * W;

    for (int ci = 0; ci < Cin; ++ci) {
        const float* q = ip + (long)ci * H * W;
        float n[4][4];
#pragma unroll
        for (int dy = 0; dy < 4; ++dy) {
            int yy = y0 - 1 + dy;
            bool yok = (unsigned)yy < (unsigned)H;
#pragma unroll
            for (int dx = 0; dx < 4; ++dx) {
                int xx = x0 - 1 + dx;
                n[dy][dx] = (yok && (unsigned)xx < (unsigned)W) ? q[(long)yy * W + xx] : 0.f;
            }
        }
        const float* ww = wp + ci * 9;
        float w0 = ww[0], w1 = ww[1], w2 = ww[2], w3 = ww[3], w4 = ww[4],
              w5 = ww[5], w6 = ww[6], w7 = ww[7], w8 = ww[8];
        a00 += n[0][0]*w0 + n[0][1]*w1 + n[0][2]*w2
             + n[1][0]*w3 + n[1][1]*w4 + n[1][2]*w5
             + n[2][0]*w6 + n[2][1]*w7 + n[2][2]*w8;
        a01 += n[0][1]*w0 + n[0][2]*w1 + n[0][3]*w2
             + n[1][1]*w3 + n[1][2]*w4 + n[1][3]*w5
             + n[2][1]*w6 + n[2][2]*w7 + n[2][3]*w8;
        a10 += n[1][0]*w0 + n[1][1]*w1 + n[1][2]*w2
             + n[2][0]*w3 + n[2][1]*w4 + n[2][2]*w5
             + n[3][0]*w6 + n[3][1]*w7 + n[3][2]*w8;
        a11 += n[1][1]*w0 + n[1][2]*w1 + n[1][3]*w2
             + n[2][1]*w3 + n[2][2]*w4 + n[2][3]*w5
             + n[3][1]*w6 + n[3][2]*w7 + n[3][3]*w8;
    }
    if (relu) {
        a00 = fmaxf(a00, 0.f); a01 = fmaxf(a01, 0.f);
        a10 = fmaxf(a10, 0.f); a11 = fmaxf(a11, 0.f);
    }

    // stores
    {
        int Co = Cout >> 2;
        int oc = co >> 2, si = (co >> 1) & 1, sj = co & 1;
#define EMIT(yy, xx, val) do {                                                     \
        float v_ = (val);                                                          \
        if (addsrc) v_ += addsrc[(((long)b * Cout + co) * H + (yy)) * W + (xx)];   \
        if (!shuffle) out[(((long)b * Cout + co) * H + (yy)) * W + (xx)] = v_;     \
        else out[(((long)b * Co + oc) * (2 * H) + 2 * (yy) + si) * (2L * W)        \
                 + 2 * (xx) + sj] = v_;                                            \
    } while (0)
        EMIT(y0, x0, a00); EMIT(y0, x0 + 1, a01);
        EMIT(y0 + 1, x0, a10); EMIT(y0 + 1, x0 + 1, a11);
#undef EMIT
    }
}

// ---------------- per-(b,c) spatial variance (ddof=1) ----------------
__global__ void k_var(const float* __restrict__ r1, float* __restrict__ v) {
    int bc = blockIdx.x;  // b*64 + c
    const float* p = r1 + (long)bc * HH * WW;
    float s = 0.f, s2 = 0.f;
    for (int i = threadIdx.x; i < HH * WW; i += blockDim.x) {
        float t = p[i]; s += t; s2 += t * t;
    }
    __shared__ float sh[256], sh2[256];
    sh[threadIdx.x] = s; sh2[threadIdx.x] = s2;
    __syncthreads();
    for (int o = 128; o > 0; o >>= 1) {
        if ((int)threadIdx.x < o) {
            sh[threadIdx.x] += sh[threadIdx.x + o];
            sh2[threadIdx.x] += sh2[threadIdx.x + o];
        }
        __syncthreads();
    }
    if (threadIdx.x == 0) {
        float n = (float)(HH * WW);
        float mean = sh[0] / n;
        v[bc] = (sh2[0] - n * mean * mean) / (n - 1.f);
    }
}

// ---------------- gates: subset-normalized sigmoid ----------------
// source channels 16..63: group A (high=False); 0..15: group B (high=True, +0.5)
__global__ void k_gate(const float* __restrict__ v, float* __restrict__ g) {
    int b = blockIdx.x; int c = threadIdx.x;  // 64 threads
    __shared__ float sv[64];
    __shared__ float stats[4];  // mA, sA, mB, sB
    sv[c] = v[b * 64 + c];
    __syncthreads();
    if (c == 0) {
        float mA = 0.f; for (int i = 16; i < 64; ++i) mA += sv[i]; mA /= 48.f;
        float sA = 0.f; for (int i = 16; i < 64; ++i) { float d = sv[i] - mA; sA += d * d; }
        sA = sqrtf(sA / 47.f);
        float mB = 0.f; for (int i = 0; i < 16; ++i) mB += sv[i]; mB /= 16.f;
        float sB = 0.f; for (int i = 0; i < 16; ++i) { float d = sv[i] - mB; sB += d * d; }
        sB = sqrtf(sB / 15.f);
        stats[0] = mA; stats[1] = sA; stats[2] = mB; stats[3] = sB;
    }
    __syncthreads();
    float gg;
    if (c >= 16) {
        float z = (sv[c] - stats[0]) / stats[1];
        gg = 0.5f / (1.f + expf(-z));
    } else {
        float z = (sv[c] - stats[2]) / stats[3];
        gg = 0.5f / (1.f + expf(-z)) + 0.5f;
    }
    g[b * 64 + c] = gg;
}

// ---------------- residual apply with channel permutation ----------------
// new c<48 <- src c+16 ; new c>=48 <- src c-48 (gates indexed by src channel)
__global__ void k_apply(float* __restrict__ t, const float* __restrict__ r1,
                        const float* __restrict__ g) {
    long total = (long)BB * CC * HH * WW;
    long idx = blockIdx.x * (long)blockDim.x + threadIdx.x;
    if (idx >= total) return;
    int hw = idx % (HH * WW); long r = idx / (HH * WW);
    int cn = r % CC; int b = (int)(r / CC);
    int cs = (cn < 48) ? cn + 16 : cn - 48;
    t[idx] += g[b * 64 + cs] * r1[((long)b * CC + cs) * (HH * WW) + hw];
}

// ---------------- fused final (single batch image): out = base + pixel_conv + final conv ----
__global__ void k_final(const float* __restrict__ base, const float* __restrict__ f,
                        const float* __restrict__ ker, const float* __restrict__ wfin,
                        const float* __restrict__ bfin, float* __restrict__ out) {
    const int H = 384, W = 384;
    long total = (long)H * W;
    long idx = blockIdx.x * (long)blockDim.x + threadIdx.x;
    if (idx >= total) return;
    int x = idx % W;
    int y = (int)(idx / W);

    // out2 = conv3(f, w_final) at (:, y, x)
    float o2[3] = {bfin[0], bfin[1], bfin[2]};
    bool interior = (x > 0 && x < W - 1 && y > 0 && y < H - 1);
    for (int ci = 0; ci < 64; ++ci) {
        const float* q = f + (long)ci * H * W;
        float n[9];
        if (interior) {
            const float* qq = q + (long)(y - 1) * W + (x - 1);
            n[0] = qq[0]; n[1] = qq[1]; n[2] = qq[2];
            n[3] = qq[W]; n[4] = qq[W + 1]; n[5] = qq[W + 2];
            n[6] = qq[2 * W]; n[7] = qq[2 * W + 1]; n[8] = qq[2 * W + 2];
        } else {
#pragma unroll
            for (int ky = 0; ky < 3; ++ky)
#pragma unroll
                for (int kx = 0; kx < 3; ++kx) {
                    int yy = y + ky - 1, xx = x + kx - 1;
                    n[ky * 3 + kx] = ((unsigned)yy < (unsigned)H && (unsigned)xx < (unsigned)W)
                                         ? q[(long)yy * W + xx] : 0.f;
                }
        }
#pragma unroll
        for (int c = 0; c < 3; ++c) {
            const float* ww = wfin + ((long)c * 64 + ci) * 9;
            o2[c] += n[0]*ww[0] + n[1]*ww[1] + n[2]*ww[2] + n[3]*ww[3] + n[4]*ww[4]
                   + n[5]*ww[5] + n[6]*ww[6] + n[7]*ww[7] + n[8]*ww[8];
        }
    }

    // out1 = pixel_conv: gather from bil (on-the-fly bilinear of base), weight by ker
    float o1[3] = {0.f, 0.f, 0.f};
#pragma unroll
    for (int n9 = 0; n9 < 9; ++n9) {
        int dx = n9 / 3 - 1, dy = n9 % 3 - 1;  // torch meshgrid 'ij': dx outer, dy inner
        int p = y + dx, q = x + dy;            // index into the 1536^2 bil image
        float bv[3];
        if (p < 0 || q < 0) {
            bv[0] = bv[1] = bv[2] = 0.f;       // zero pad at -1
        } else {
            float syf = 0.25f * p - 0.375f;    // (p+0.5)/4 - 0.5 into base's 384 grid
            float sxf = 0.25f * q - 0.375f;
            int iy0 = (int)floorf(syf); float fy = syf - iy0;
            int ix0 = (int)floorf(sxf); float fx = sxf - ix0;
            int iy1 = iy0 + 1, ix1 = ix0 + 1;
            iy0 = min(max(iy0, 0), H - 1); iy1 = min(max(iy1, 0), H - 1);
            ix0 = min(max(ix0, 0), W - 1); ix1 = min(max(ix1, 0), W - 1);
#pragma unroll
            for (int c = 0; c < 3; ++c) {
                const float* bp = base + (long)c * H * W;
                bv[c] = (1.f - fy) * ((1.f - fx) * bp[iy0 * W + ix0] + fx * bp[iy0 * W + ix1])
                      +        fy  * ((1.f - fx) * bp[iy1 * W + ix0] + fx * bp[iy1 * W + ix1]);
            }
        }
#pragma unroll
        for (int c = 0; c < 3; ++c)
            o1[c] += bv[c] * ker[((long)(n9 * 3 + c) * H + y) * W + x];
    }

#pragma unroll
    for (int c = 0; c < 3; ++c) {
        long oi = ((long)c * H + y) * W + x;
        out[oi] = base[oi] + o2[c] + o1[c];
    }
}

// ==========================================================================
extern "C" void kernel_launch(void* const* d_in, const int* in_sizes, int n_in,
                              void* d_out, int out_size, void* d_ws, size_t ws_size,
                              hipStream_t stream) {
    const float* x       = (const float*)d_in[0];
    const float* w_first = (const float*)d_in[1];
    const float* b_first = (const float*)d_in[2];
    const float* w_blk1  = (const float*)d_in[3];
    const float* b_blk1  = (const float*)d_in[4];
    const float* w_blk2  = (const float*)d_in[5];
    const float* b_blk2  = (const float*)d_in[6];
    const float* w_after = (const float*)d_in[7];
    const float* b_after = (const float*)d_in[8];
    const float* w_up1   = (const float*)d_in[9];
    const float* b_up1   = (const float*)d_in[10];
    const float* w_up2   = (const float*)d_in[11];
    const float* b_up2   = (const float*)d_in[12];
    const float* w_fc1   = (const float*)d_in[13];
    const float* b_fc1   = (const float*)d_in[14];
    const float* w_fc2   = (const float*)d_in[15];
    const float* b_fc2   = (const float*)d_in[16];
    const float* w_kconv = (const float*)d_in[17];
    const float* b_kconv = (const float*)d_in[18];
    const float* w_final = (const float*)d_in[19];
    const float* b_final = (const float*)d_in[20];
    float* outp = (float*)d_out;

    // ---- workspace layout (bytes, 256-aligned). Peak ~130 MB. ----
    char* ws = (char*)d_ws;
    size_t off = 0;
    auto alloc = [&](size_t bytes) {
        size_t o = off;
        off += (bytes + 255) & ~(size_t)255;
        return o;
    };
    const size_t SM   = (size_t)BB * CC * HH * WW * 4;      // 9.4 MB full-batch small map
    const size_t BG1  = (size_t)CC * 384 * 384 * 4;         // 37.7 MB single-batch big map
    float* base = (float*)(ws + alloc((size_t)BB * 3 * 384 * 384 * 4));  // 7.1 MB
    float* h0   = (float*)(ws + alloc(SM));
    float* t    = (float*)(ws + alloc(SM));
    float* ta   = (float*)(ws + alloc(SM));
    float* r1   = (float*)(ws + alloc(SM));
    float* vbuf = (float*)(ws + alloc(BB * CC * 4));
    float* gbuf = (float*)(ws + alloc(BB * CC * 4));
    float* u1b  = (float*)(ws + alloc((size_t)CC * 192 * 192 * 4));      // 9.4 MB
    float* slotA = (float*)(ws + alloc(BG1));               // u2_b, then f_b
    float* slotB = (float*)(ws + alloc(BG1));               // v1_b, then ker_b
    (void)ws_size; (void)in_sizes; (void)n_in; (void)out_size;

    const int TPB = 256;
    auto cgrid = [&](long total) { return dim3(ceil_div(total, TPB)); };

    // 1. base = bilinear4x(x) : [4,3,384,384]
    {
        long tot = (long)BB * 3 * 384 * 384;
        k_bilinear4x<<<cgrid(tot), TPB, 0, stream>>>(x, base, BB, 3, HH, WW);
    }
    // 2. h0 = conv3(x, w_first)
    {
        long tot = (long)BB * CC * (HH / 2) * (WW / 2);
        k_conv3<<<cgrid(tot), TPB, 0, stream>>>(x, w_first, b_first, nullptr, h0,
                                                BB, 3, CC, HH, WW, 0, 0);
    }
    // 3. t = h0
    hipMemcpyAsync(t, h0, SM, hipMemcpyDeviceToDevice, stream);

    // 4. MAM blocks
    long sm_tiles = (long)BB * CC * (HH / 2) * (WW / 2);
    long sm_elems = (long)BB * CC * HH * WW;
    for (int i = 0; i < 8; ++i) {
        const float* wb1 = w_blk1 + (long)i * CC * CC * 9;
        const float* bb1 = b_blk1 + (long)i * CC;
        const float* wb2 = w_blk2 + (long)i * CC * CC * 9;
        const float* bb2 = b_blk2 + (long)i * CC;
        k_conv3<<<cgrid(sm_tiles), TPB, 0, stream>>>(t, wb1, bb1, nullptr, ta,
                                                     BB, CC, CC, HH, WW, 1, 0);
        k_conv3<<<cgrid(sm_tiles), TPB, 0, stream>>>(ta, wb2, bb2, nullptr, r1,
                                                     BB, CC, CC, HH, WW, 0, 0);
        k_var<<<dim3(BB * CC), dim3(256), 0, stream>>>(r1, vbuf);
        k_gate<<<dim3(BB), dim3(64), 0, stream>>>(vbuf, gbuf);
        k_apply<<<cgrid(sm_elems), TPB, 0, stream>>>(t, r1, gbuf);
    }

    // 5. ta = conv3(t, w_after) + h0
    k_conv3<<<cgrid(sm_tiles), TPB, 0, stream>>>(t, w_after, b_after, h0, ta,
                                                 BB, CC, CC, HH, WW, 0, 0);

    // 6..11: per-batch tail at 384^2 to keep workspace small
    for (int b = 0; b < BB; ++b) {
        const float* ta_b   = ta + (long)b * CC * HH * WW;
        const float* base_b = base + (long)b * 3 * 384 * 384;
        float* out_b        = outp + (long)b * 3 * 384 * 384;

        // u1_b = shuffle(conv3(ta_b, w_up1)) : [64,192,192]
        {
            long tot = (long)256 * (HH / 2) * (WW / 2);
            k_conv3<<<cgrid(tot), TPB, 0, stream>>>(ta_b, w_up1, b_up1, nullptr, u1b,
                                                    1, CC, 256, HH, WW, 0, 1);
        }
        // u2_b = shuffle(conv3(u1_b, w_up2)) : [64,384,384] -> slotA
        {
            long tot = (long)256 * (192 / 2) * (192 / 2);
            k_conv3<<<cgrid(tot), TPB, 0, stream>>>(u1b, w_up2, b_up2, nullptr, slotA,
                                                    1, CC, 256, 192, 192, 0, 1);
        }
        long bg_tiles = (long)CC * (384 / 2) * (384 / 2);
        // v1_b = conv3(u2_b, w_fc1) -> slotB
        k_conv3<<<cgrid(bg_tiles), TPB, 0, stream>>>(slotA, w_fc1, b_fc1, nullptr, slotB,
                                                     1, CC, CC, 384, 384, 0, 0);
        // f_b = conv3(v1_b, w_fc2) -> slotA (u2 dead)
        k_conv3<<<cgrid(bg_tiles), TPB, 0, stream>>>(slotB, w_fc2, b_fc2, nullptr, slotA,
                                                     1, CC, CC, 384, 384, 0, 0);
        // ker_b = conv3(f_b, w_kconv) -> slotB (v1 dead) : [27,384,384]
        {
            long tot = (long)27 * (384 / 2) * (384 / 2);
            k_conv3<<<cgrid(tot), TPB, 0, stream>>>(slotA, w_kconv, b_kconv, nullptr, slotB,
                                                    1, CC, 27, 384, 384, 0, 0);
        }
        // out_b = base_b + pixel_conv(ker_b, bil(base_b)) + conv3(f_b, w_final)
        {
            long tot = (long)384 * 384;
            k_final<<<cgrid(tot), TPB, 0, stream>>>(base_b, slotA, slotB, w_final, b_final, out_b);
        }
    }
}

// Round 4
// 6353.750 us; speedup vs baseline: 3.5172x; 3.5172x over previous
//
#include <hip/hip_runtime.h>
#include <hip/hip_bf16.h>
#include <math.h>

#define BB 4
#define CC 64
#define HH 96
#define WW 96

typedef __attribute__((ext_vector_type(8))) short bf16x8;   // 8 bf16 in 4 VGPRs
typedef __attribute__((ext_vector_type(4))) float f32x4;

static inline int ceil_div(long a, long b) { return (int)((a + b - 1) / b); }

__device__ __forceinline__ float b2f(unsigned short u) {
    union { unsigned int i; float f; } v; v.i = ((unsigned int)u) << 16; return v.f;
}
__device__ __forceinline__ unsigned short f2b(float f) {
    union { float f; unsigned int i; } v; v.f = f;
    unsigned int r = v.i + 0x7fffu + ((v.i >> 16) & 1u);   // RTNE
    return (unsigned short)(r >> 16);
}

// ---------------- bilinear 4x upsample (fp32, unchanged) ----------------
__global__ void k_bilinear4x(const float* __restrict__ in, float* __restrict__ out,
                             int B, int C, int Hin, int Win) {
    int Hout = Hin * 4, Wout = Win * 4;
    long total = (long)B * C * Hout * Wout;
    long idx = blockIdx.x * (long)blockDim.x + threadIdx.x;
    if (idx >= total) return;
    int x = idx % Wout; long r = idx / Wout;
    int y = r % Hout; r /= Hout;
    int c = r % C; int b = (int)(r / C);
    float sy = 0.25f * (y + 0.5f) - 0.5f;
    float sx = 0.25f * (x + 0.5f) - 0.5f;
    int iy0 = (int)floorf(sy); float fy = sy - iy0;
    int ix0 = (int)floorf(sx); float fx = sx - ix0;
    int iy1 = iy0 + 1, ix1 = ix0 + 1;
    iy0 = min(max(iy0, 0), Hin - 1); iy1 = min(max(iy1, 0), Hin - 1);
    ix0 = min(max(ix0, 0), Win - 1); ix1 = min(max(ix1, 0), Win - 1);
    const float* p = in + ((long)(b * C + c) * Hin) * Win;
    float v = (1.f - fy) * ((1.f - fx) * p[iy0 * Win + ix0] + fx * p[iy0 * Win + ix1])
            +        fy  * ((1.f - fx) * p[iy1 * Win + ix0] + fx * p[iy1 * Win + ix1]);
    out[idx] = v;
}

// ---------------- weight prep: fp32 OIHW -> bf16 [ng][tap][n][cin] ----------------
__global__ void k_wprep(const float* __restrict__ src, unsigned short* __restrict__ dst,
                        int CoutReal, int ngroups) {
    long tot = (long)ngroups * 9 * 4096;
    long idx = blockIdx.x * 256L + threadIdx.x;
    if (idx >= tot) return;
    const float* s = src + (size_t)blockIdx.y * CoutReal * 64 * 9;
    unsigned short* d = dst + (size_t)blockIdx.y * tot;
    int ci = (int)(idx & 63);
    int n  = (int)((idx >> 6) & 63);
    long t2 = idx >> 12;
    int tap = (int)(t2 % 9);
    int ng  = (int)(t2 / 9);
    int co = ng * 64 + n;
    float v = (co < CoutReal) ? s[((size_t)co * 64 + ci) * 9 + tap] : 0.f;
    d[idx] = f2b(v);
}

// ---------------- first conv: Cin=3 fp32 NCHW -> bf16 NHWC [B][96*96][64] ----------------
__global__ void k_first(const float* __restrict__ x, const float* __restrict__ w,
                        const float* __restrict__ bias, unsigned short* __restrict__ h0) {
    __shared__ float lw[64 * 27];
    __shared__ float lb[64];
    for (int i = threadIdx.x; i < 1728; i += 256) lw[i] = w[i];
    if (threadIdx.x < 64) lb[threadIdx.x] = bias[threadIdx.x];
    __syncthreads();
    int pix = blockIdx.x * 256 + threadIdx.x;
    if (pix >= 9216) return;
    int bimg = blockIdx.z;
    int y = pix / 96, x0 = pix - y * 96;
    float nb[27];
#pragma unroll
    for (int ci = 0; ci < 3; ++ci)
#pragma unroll
        for (int ky = 0; ky < 3; ++ky)
#pragma unroll
            for (int kx = 0; kx < 3; ++kx) {
                int py = y + ky - 1, px = x0 + kx - 1;
                nb[ci * 9 + ky * 3 + kx] =
                    ((unsigned)py < 96u && (unsigned)px < 96u)
                        ? x[((size_t)(bimg * 3 + ci) * 9216) + py * 96 + px] : 0.f;
            }
    unsigned short* orow = h0 + ((size_t)bimg * 9216 + pix) * 64;
    for (int cg = 0; cg < 8; ++cg) {
        float a[8];
#pragma unroll
        for (int u = 0; u < 8; ++u) {
            int co = cg * 8 + u;
            float s = lb[co];
#pragma unroll
            for (int t = 0; t < 27; ++t) s += nb[t] * lw[co * 27 + t];
            a[u] = s;
        }
        bf16x8 pk;
#pragma unroll
        for (int u = 0; u < 8; ++u) pk[u] = (short)f2b(a[u]);
        *(bf16x8*)(orow + cg * 8) = pk;
    }
}

// ---------------- MFMA implicit-GEMM 3x3 conv, Cin=64, N-group=64 ----------------
// in:  bf16 NHWC [z][H*W][64]
// wp:  bf16 [ngroup][tap][n][cin] (per-blockIdx.y slice staged to LDS, XOR-swizzled)
// out: normal -> bf16 [z][H*W][outCs] (store n<CoutReal)
//      shuffle -> bf16 [z][2H*2W][64] pixel_shuffle(r=2) fused
// flags: 1=relu, 2=shuffle, 4=add addsrc (normal path only)
template<int MSUB>
__global__ __launch_bounds__(256, 2)
void k_mfconv(const unsigned short* __restrict__ in, const unsigned short* __restrict__ wp,
              const float* __restrict__ bias, const unsigned short* __restrict__ addsrc,
              unsigned short* __restrict__ out,
              int H, int W, int CoutReal, int outCs,
              long inImgStride, long outImgStride, int flags) {
    __shared__ uint4 ldsWv[4608];   // 73728 B
    const int tid = threadIdx.x;
    const uint4* wsrc = (const uint4*)(wp + (size_t)blockIdx.y * (9 * 64 * 64));
#pragma unroll
    for (int i = 0; i < 18; ++i) {
        int c = tid + i * 256;                 // 16B chunk id: [tap][n][g]
        uint4 v = wsrc[c];
        int tap = c >> 9, n = (c >> 3) & 63, g = c & 7;
        ldsWv[(tap * 64 + n) * 8 + (g ^ (n & 7))] = v;
    }
    __syncthreads();
    const bf16x8* ldsF = (const bf16x8*)ldsWv;

    const int lane = tid & 63, wv = tid >> 6;
    const int lr = lane & 15, lk = lane >> 4;
    const int nBase = blockIdx.y * 64;
    const unsigned short* inImg = in + (size_t)blockIdx.z * inImgStride;
    unsigned short* outImg = out + (size_t)blockIdx.z * outImgStride;
    const unsigned short* addImg = addsrc ? addsrc + (size_t)blockIdx.z * outImgStride : (const unsigned short*)0;

    const int mBase = blockIdx.x * (MSUB * 64) + wv * (MSUB * 16);
    int ys[MSUB], xs[MSUB];
#pragma unroll
    for (int i = 0; i < MSUB; ++i) {
        int m0 = mBase + i * 16;              // 16 consecutive m stay in one row (W%16==0)
        ys[i] = m0 / W; xs[i] = m0 - ys[i] * W;
    }

    f32x4 acc[MSUB][4];
#pragma unroll
    for (int j = 0; j < 4; ++j) {
        int n = nBase + j * 16 + lr;
        float bv = (n < CoutReal) ? bias[n] : 0.f;
#pragma unroll
        for (int i = 0; i < MSUB; ++i) acc[i][j] = (f32x4){bv, bv, bv, bv};
    }

#pragma unroll
    for (int ky = 0; ky < 3; ++ky) {
#pragma unroll
        for (int kx = 0; kx < 3; ++kx) {
            const int tap = ky * 3 + kx;
#pragma unroll
            for (int kk = 0; kk < 2; ++kk) {
                bf16x8 bf[4];
#pragma unroll
                for (int j = 0; j < 4; ++j) {
                    int n = j * 16 + lr;
                    bf[j] = ldsF[(tap * 64 + n) * 8 + (((kk << 2) | lk) ^ (n & 7))];
                }
                const int koff = kk * 32 + lk * 8;
#pragma unroll
                for (int i = 0; i < MSUB; ++i) {
                    int py = ys[i] + ky - 1;
                    int px = xs[i] + lr + kx - 1;
                    bf16x8 af = {0, 0, 0, 0, 0, 0, 0, 0};
                    if ((unsigned)py < (unsigned)H && (unsigned)px < (unsigned)W)
                        af = *(const bf16x8*)(inImg + ((size_t)py * W + px) * 64 + koff);
#pragma unroll
                    for (int j = 0; j < 4; ++j)
                        acc[i][j] = __builtin_amdgcn_mfma_f32_16x16x32_bf16(af, bf[j], acc[i][j], 0, 0, 0);
                }
            }
        }
    }

    const bool doRelu = flags & 1, doShuf = flags & 2, doAdd = flags & 4;
#pragma unroll
    for (int i = 0; i < MSUB; ++i) {
#pragma unroll
        for (int j = 0; j < 4; ++j) {
            int n = nBase + j * 16 + lr;
            f32x4 a = acc[i][j];
#pragma unroll
            for (int r = 0; r < 4; ++r) {
                float v = a[r];
                if (doRelu) v = fmaxf(v, 0.f);
                int y = ys[i], xcol = xs[i] + lk * 4 + r;   // D row = (lane>>4)*4 + r
                if (!doShuf) {
                    if (n < CoutReal) {
                        size_t o = ((size_t)y * W + xcol) * outCs + n;
                        if (doAdd) v += b2f(addImg[o]);
                        outImg[o] = f2b(v);
                    }
                } else {
                    int oc = n >> 2, si = (n >> 1) & 1, sj = n & 1;
                    size_t o = ((size_t)(2 * y + si) * (2 * W) + (2 * xcol + sj)) * 64 + oc;
                    outImg[o] = f2b(v);
                }
            }
        }
    }
}

// ---------------- per-(b,c) spatial variance (ddof=1) on bf16 NHWC ----------------
__global__ void k_var(const unsigned short* __restrict__ r1, float* __restrict__ v) {
    int b = blockIdx.x;
    int c = threadIdx.x & 63, seg = threadIdx.x >> 6;
    float s = 0.f, s2 = 0.f;
    for (int p = seg; p < 9216; p += 4) {
        float t = b2f(r1[((size_t)b * 9216 + p) * 64 + c]);
        s += t; s2 += t * t;
    }
    __shared__ float sh[2][256];
    sh[0][threadIdx.x] = s; sh[1][threadIdx.x] = s2;
    __syncthreads();
    if (seg == 0) {
#pragma unroll
        for (int k = 1; k < 4; ++k) { s += sh[0][c + 64 * k]; s2 += sh[1][c + 64 * k]; }
        float n = 9216.f;
        float mean = s / n;
        v[b * 64 + c] = (s2 - n * mean * mean) / (n - 1.f);
    }
}

// ---------------- gates: subset-normalized sigmoid ----------------
__global__ void k_gate(const float* __restrict__ v, float* __restrict__ g) {
    int b = blockIdx.x; int c = threadIdx.x;
    __shared__ float sv[64];
    __shared__ float stats[4];
    sv[c] = v[b * 64 + c];
    __syncthreads();
    if (c == 0) {
        float mA = 0.f; for (int i = 16; i < 64; ++i) mA += sv[i]; mA /= 48.f;
        float sA = 0.f; for (int i = 16; i < 64; ++i) { float d = sv[i] - mA; sA += d * d; }
        sA = sqrtf(sA / 47.f);
        float mB = 0.f; for (int i = 0; i < 16; ++i) mB += sv[i]; mB /= 16.f;
        float sB = 0.f; for (int i = 0; i < 16; ++i) { float d = sv[i] - mB; sB += d * d; }
        sB = sqrtf(sB / 15.f);
        stats[0] = mA; stats[1] = sA; stats[2] = mB; stats[3] = sB;
    }
    __syncthreads();
    float gg;
    if (c >= 16) {
        float z = (sv[c] - stats[0]) / stats[1];
        gg = 0.5f / (1.f + expf(-z));
    } else {
        float z = (sv[c] - stats[2]) / stats[3];
        gg = 0.5f / (1.f + expf(-z)) + 0.5f;
    }
    g[b * 64 + c] = gg;
}

// ---------------- residual apply with channel permutation (bf16 NHWC) ----------------
__global__ void k_apply(unsigned short* __restrict__ t, const unsigned short* __restrict__ r1,
                        const float* __restrict__ g) {
    long total = (long)BB * 9216 * 64;
    long idx = blockIdx.x * 256L + threadIdx.x;
    if (idx >= total) return;
    int cn = (int)(idx & 63);
    long p = idx >> 6;                 // global pixel (b*9216 + pix)
    int b = (int)(p / 9216);
    int cs = (cn < 48) ? cn + 16 : cn - 48;
    float val = b2f(t[idx]) + g[b * 64 + cs] * b2f(r1[(p << 6) + cs]);
    t[idx] = f2b(val);
}

// ---------------- fused final (one image): out = base + pixel_conv + final conv ----------------
// f: bf16 NHWC [384*384][64]; ker: bf16 [384*384][32] (27 used); base/out fp32 NCHW
__global__ void k_final(const float* __restrict__ base, const unsigned short* __restrict__ f,
                        const unsigned short* __restrict__ ker, const float* __restrict__ wfin,
                        const float* __restrict__ bfin, float* __restrict__ out) {
    const int H = 384, W = 384;
    __shared__ float lw[3 * 64 * 9];
    for (int i = threadIdx.x; i < 1728; i += 256) lw[i] = wfin[i];
    __syncthreads();
    long idx = blockIdx.x * 256L + threadIdx.x;
    if (idx >= (long)H * W) return;
    int x = (int)(idx % W);
    int y = (int)(idx / W);

    float o2[3] = {bfin[0], bfin[1], bfin[2]};
#pragma unroll
    for (int ky = 0; ky < 3; ++ky)
#pragma unroll
        for (int kx = 0; kx < 3; ++kx) {
            int tap = ky * 3 + kx;
            int py = y + ky - 1, px = x + kx - 1;
            if ((unsigned)py >= (unsigned)H || (unsigned)px >= (unsigned)W) continue;
            const unsigned short* fp = f + ((size_t)py * W + px) * 64;
            for (int c8 = 0; c8 < 8; ++c8) {
                bf16x8 vv = *(const bf16x8*)(fp + c8 * 8);
#pragma unroll
                for (int u = 0; u < 8; ++u) {
                    float fv = b2f((unsigned short)vv[u]);
                    int ci = c8 * 8 + u;
                    o2[0] += fv * lw[(0 * 64 + ci) * 9 + tap];
                    o2[1] += fv * lw[(1 * 64 + ci) * 9 + tap];
                    o2[2] += fv * lw[(2 * 64 + ci) * 9 + tap];
                }
            }
        }

    // pixel_conv: gather from on-the-fly bilinear of base (top-left 385x385 corner quirk)
    float o1[3] = {0.f, 0.f, 0.f};
    const unsigned short* kp = ker + (size_t)idx * 32;
#pragma unroll
    for (int n9 = 0; n9 < 9; ++n9) {
        int dx = n9 / 3 - 1, dy = n9 % 3 - 1;   // torch meshgrid 'ij': dx outer, dy inner
        int p = y + dx, q = x + dy;
        float bv[3];
        if (p < 0 || q < 0) {
            bv[0] = bv[1] = bv[2] = 0.f;
        } else {
            float syf = 0.25f * p - 0.375f;
            float sxf = 0.25f * q - 0.375f;
            int iy0 = (int)floorf(syf); float fy = syf - iy0;
            int ix0 = (int)floorf(sxf); float fx = sxf - ix0;
            int iy1 = iy0 + 1, ix1 = ix0 + 1;
            iy0 = min(max(iy0, 0), H - 1); iy1 = min(max(iy1, 0), H - 1);
            ix0 = min(max(ix0, 0), W - 1); ix1 = min(max(ix1, 0), W - 1);
#pragma unroll
            for (int c = 0; c < 3; ++c) {
                const float* bp = base + (long)c * H * W;
                bv[c] = (1.f - fy) * ((1.f - fx) * bp[iy0 * W + ix0] + fx * bp[iy0 * W + ix1])
                      +        fy  * ((1.f - fx) * bp[iy1 * W + ix0] + fx * bp[iy1 * W + ix1]);
            }
        }
#pragma unroll
        for (int c = 0; c < 3; ++c)
            o1[c] += bv[c] * b2f(kp[n9 * 3 + c]);
    }

#pragma unroll
    for (int c = 0; c < 3; ++c) {
        long oi = ((long)c * H + y) * W + x;
        out[oi] = base[oi] + o2[c] + o1[c];
    }
}

// ==========================================================================
extern "C" void kernel_launch(void* const* d_in, const int* in_sizes, int n_in,
                              void* d_out, int out_size, void* d_ws, size_t ws_size,
                              hipStream_t stream) {
    const float* x       = (const float*)d_in[0];
    const float* w_first = (const float*)d_in[1];
    const float* b_first = (const float*)d_in[2];
    const float* w_blk1  = (const float*)d_in[3];
    const float* b_blk1  = (const float*)d_in[4];
    const float* w_blk2  = (const float*)d_in[5];
    const float* b_blk2  = (const float*)d_in[6];
    const float* w_after = (const float*)d_in[7];
    const float* b_after = (const float*)d_in[8];
    const float* w_up1   = (const float*)d_in[9];
    const float* b_up1   = (const float*)d_in[10];
    const float* w_up2   = (const float*)d_in[11];
    const float* b_up2   = (const float*)d_in[12];
    const float* w_fc1   = (const float*)d_in[13];
    const float* b_fc1   = (const float*)d_in[14];
    const float* w_fc2   = (const float*)d_in[15];
    const float* b_fc2   = (const float*)d_in[16];
    const float* w_kconv = (const float*)d_in[17];
    const float* b_kconv = (const float*)d_in[18];
    const float* w_final = (const float*)d_in[19];
    const float* b_final = (const float*)d_in[20];
    float* outp = (float*)d_out;
    (void)in_sizes; (void)n_in; (void)out_size; (void)ws_size;

    typedef unsigned short u16;
    char* ws = (char*)d_ws;
    size_t off = 0;
    auto alloc = [&](size_t bytes) {
        size_t o = off; off += (bytes + 255) & ~(size_t)255; return o;
    };
    const size_t SMB = (size_t)BB * 9216 * 64 * 2;       // 4.72 MB bf16 small map
    float* base = (float*)(ws + alloc((size_t)BB * 3 * 147456 * 4));   // 7.1 MB
    u16* h0   = (u16*)(ws + alloc(SMB));
    u16* t    = (u16*)(ws + alloc(SMB));
    u16* ta   = (u16*)(ws + alloc(SMB));
    u16* r1   = (u16*)(ws + alloc(SMB));
    float* vbuf = (float*)(ws + alloc(BB * 64 * 4));
    float* gbuf = (float*)(ws + alloc(BB * 64 * 4));
    u16* u1   = (u16*)(ws + alloc((size_t)BB * 36864 * 64 * 2));       // 18.9 MB
    u16* bigA = (u16*)(ws + alloc((size_t)147456 * 64 * 2));           // 18.9 MB (per-batch)
    u16* bigB = (u16*)(ws + alloc((size_t)147456 * 64 * 2));           // 18.9 MB
    u16* kerb = (u16*)(ws + alloc((size_t)147456 * 32 * 2));           // 9.4 MB
    // bf16 weights
    u16* wpB1 = (u16*)(ws + alloc((size_t)8 * 9 * 4096 * 2));
    u16* wpB2 = (u16*)(ws + alloc((size_t)8 * 9 * 4096 * 2));
    u16* wpAf = (u16*)(ws + alloc((size_t)9 * 4096 * 2));
    u16* wpU1 = (u16*)(ws + alloc((size_t)4 * 9 * 4096 * 2));
    u16* wpU2 = (u16*)(ws + alloc((size_t)4 * 9 * 4096 * 2));
    u16* wpF1 = (u16*)(ws + alloc((size_t)9 * 4096 * 2));
    u16* wpF2 = (u16*)(ws + alloc((size_t)9 * 4096 * 2));
    u16* wpKc = (u16*)(ws + alloc((size_t)9 * 4096 * 2));

    // ---- weight prep ----
    k_wprep<<<dim3(144, 8), 256, 0, stream>>>(w_blk1, wpB1, 64, 1);
    k_wprep<<<dim3(144, 8), 256, 0, stream>>>(w_blk2, wpB2, 64, 1);
    k_wprep<<<dim3(144, 1), 256, 0, stream>>>(w_after, wpAf, 64, 1);
    k_wprep<<<dim3(576, 1), 256, 0, stream>>>(w_up1, wpU1, 256, 4);
    k_wprep<<<dim3(576, 1), 256, 0, stream>>>(w_up2, wpU2, 256, 4);
    k_wprep<<<dim3(144, 1), 256, 0, stream>>>(w_fc1, wpF1, 64, 1);
    k_wprep<<<dim3(144, 1), 256, 0, stream>>>(w_fc2, wpF2, 64, 1);
    k_wprep<<<dim3(144, 1), 256, 0, stream>>>(w_kconv, wpKc, 27, 1);

    // ---- base + first ----
    k_bilinear4x<<<dim3(6912), 256, 0, stream>>>(x, base, BB, 3, HH, WW);
    k_first<<<dim3(36, 1, BB), 256, 0, stream>>>(x, w_first, b_first, h0);
    hipMemcpyAsync(t, h0, SMB, hipMemcpyDeviceToDevice, stream);

    const long smStride = 9216L * 64;
    // ---- MAM blocks ----
    for (int i = 0; i < 8; ++i) {
        const u16* wb1 = wpB1 + (size_t)i * 9 * 4096;
        const u16* wb2 = wpB2 + (size_t)i * 9 * 4096;
        k_mfconv<2><<<dim3(72, 1, BB), 256, 0, stream>>>(
            t, wb1, b_blk1 + (size_t)i * 64, nullptr, ta, 96, 96, 64, 64, smStride, smStride, 1);
        k_mfconv<2><<<dim3(72, 1, BB), 256, 0, stream>>>(
            ta, wb2, b_blk2 + (size_t)i * 64, nullptr, r1, 96, 96, 64, 64, smStride, smStride, 0);
        k_var<<<dim3(BB), 256, 0, stream>>>(r1, vbuf);
        k_gate<<<dim3(BB), 64, 0, stream>>>(vbuf, gbuf);
        k_apply<<<dim3(9216), 256, 0, stream>>>(t, r1, gbuf);
    }

    // ---- after conv (+h0 residual) ----
    k_mfconv<2><<<dim3(72, 1, BB), 256, 0, stream>>>(
        t, wpAf, b_after, h0, ta, 96, 96, 64, 64, smStride, smStride, 4);

    // ---- up1 (pixel_shuffle fused), full batch ----
    k_mfconv<4><<<dim3(36, 4, BB), 256, 0, stream>>>(
        ta, wpU1, b_up1, nullptr, u1, 96, 96, 256, 64, smStride, 36864L * 64, 2);

    // ---- per-batch 384^2 tail ----
    for (int b = 0; b < BB; ++b) {
        const u16* u1b = u1 + (size_t)b * 36864 * 64;
        const float* base_b = base + (size_t)b * 3 * 147456;
        float* out_b = outp + (size_t)b * 3 * 147456;
        // up2: 192^2 -> shuffle -> bigA [384^2][64]
        k_mfconv<4><<<dim3(144, 4, 1), 256, 0, stream>>>(
            u1b, wpU2, b_up2, nullptr, bigA, 192, 192, 256, 64, 0, 0, 2);
        // fc1: bigA -> bigB
        k_mfconv<4><<<dim3(576, 1, 1), 256, 0, stream>>>(
            bigA, wpF1, b_fc1, nullptr, bigB, 384, 384, 64, 64, 0, 0, 0);
        // fc2: bigB -> bigA (= f)
        k_mfconv<4><<<dim3(576, 1, 1), 256, 0, stream>>>(
            bigB, wpF2, b_fc2, nullptr, bigA, 384, 384, 64, 64, 0, 0, 0);
        // kconv: f -> kerb (27 of 32 ch)
        k_mfconv<4><<<dim3(576, 1, 1), 256, 0, stream>>>(
            bigA, wpKc, b_kconv, nullptr, kerb, 384, 384, 27, 32, 0, 0, 0);
        // final fuse
        k_final<<<dim3(576), 256, 0, stream>>>(base_b, bigA, kerb, w_final, b_final, out_b);
    }
}

// Round 5
// 1584.565 us; speedup vs baseline: 14.1034x; 4.0098x over previous
//
#include <hip/hip_runtime.h>
#include <hip/hip_bf16.h>
#include <math.h>

#define BB 4
#define CC 64
#define HH 96
#define WW 96

typedef __attribute__((ext_vector_type(8))) short bf16x8;   // 8 bf16 in 4 VGPRs
typedef __attribute__((ext_vector_type(4))) float f32x4;

static inline int ceil_div(long a, long b) { return (int)((a + b - 1) / b); }

__device__ __forceinline__ float b2f(unsigned short u) {
    union { unsigned int i; float f; } v; v.i = ((unsigned int)u) << 16; return v.f;
}
__device__ __forceinline__ unsigned short f2b(float f) {
    union { float f; unsigned int i; } v; v.f = f;
    unsigned int r = v.i + 0x7fffu + ((v.i >> 16) & 1u);   // RTNE
    return (unsigned short)(r >> 16);
}

// ---------------- bilinear 4x upsample (fp32) ----------------
__global__ void k_bilinear4x(const float* __restrict__ in, float* __restrict__ out,
                             int B, int C, int Hin, int Win) {
    int Hout = Hin * 4, Wout = Win * 4;
    long total = (long)B * C * Hout * Wout;
    long idx = blockIdx.x * (long)blockDim.x + threadIdx.x;
    if (idx >= total) return;
    int x = idx % Wout; long r = idx / Wout;
    int y = r % Hout; r /= Hout;
    int c = r % C; int b = (int)(r / C);
    float sy = 0.25f * (y + 0.5f) - 0.5f;
    float sx = 0.25f * (x + 0.5f) - 0.5f;
    int iy0 = (int)floorf(sy); float fy = sy - iy0;
    int ix0 = (int)floorf(sx); float fx = sx - ix0;
    int iy1 = iy0 + 1, ix1 = ix0 + 1;
    iy0 = min(max(iy0, 0), Hin - 1); iy1 = min(max(iy1, 0), Hin - 1);
    ix0 = min(max(ix0, 0), Win - 1); ix1 = min(max(ix1, 0), Win - 1);
    const float* p = in + ((long)(b * C + c) * Hin) * Win;
    float v = (1.f - fy) * ((1.f - fx) * p[iy0 * Win + ix0] + fx * p[iy0 * Win + ix1])
            +        fy  * ((1.f - fx) * p[iy1 * Win + ix0] + fx * p[iy1 * Win + ix1]);
    out[idx] = v;
}

// ---------------- weight prep: fp32 OIHW -> bf16 [ng][tap][n][cin] ----------------
__global__ void k_wprep(const float* __restrict__ src, unsigned short* __restrict__ dst,
                        int CoutReal, int ngroups) {
    long tot = (long)ngroups * 9 * 4096;
    long idx = blockIdx.x * 256L + threadIdx.x;
    if (idx >= tot) return;
    const float* s = src + (size_t)blockIdx.y * CoutReal * 64 * 9;
    unsigned short* d = dst + (size_t)blockIdx.y * tot;
    int ci = (int)(idx & 63);
    int n  = (int)((idx >> 6) & 63);
    long t2 = idx >> 12;
    int tap = (int)(t2 % 9);
    int ng  = (int)(t2 / 9);
    int co = ng * 64 + n;
    float v = (co < CoutReal) ? s[((size_t)co * 64 + ci) * 9 + tap] : 0.f;
    d[idx] = f2b(v);
}

// ---------------- first conv: Cin=3 fp32 NCHW -> bf16 NHWC [B][96*96][64] ----------------
__global__ void k_first(const float* __restrict__ x, const float* __restrict__ w,
                        const float* __restrict__ bias, unsigned short* __restrict__ h0) {
    __shared__ float lw[64 * 27];
    __shared__ float lb[64];
    for (int i = threadIdx.x; i < 1728; i += 256) lw[i] = w[i];
    if (threadIdx.x < 64) lb[threadIdx.x] = bias[threadIdx.x];
    __syncthreads();
    int pix = blockIdx.x * 256 + threadIdx.x;
    if (pix >= 9216) return;
    int bimg = blockIdx.z;
    int y = pix / 96, x0 = pix - y * 96;
    float nb[27];
#pragma unroll
    for (int ci = 0; ci < 3; ++ci)
#pragma unroll
        for (int ky = 0; ky < 3; ++ky)
#pragma unroll
            for (int kx = 0; kx < 3; ++kx) {
                int py = y + ky - 1, px = x0 + kx - 1;
                nb[ci * 9 + ky * 3 + kx] =
                    ((unsigned)py < 96u && (unsigned)px < 96u)
                        ? x[((size_t)(bimg * 3 + ci) * 9216) + py * 96 + px] : 0.f;
            }
    unsigned short* orow = h0 + ((size_t)bimg * 9216 + pix) * 64;
    for (int cg = 0; cg < 8; ++cg) {
        float a[8];
#pragma unroll
        for (int u = 0; u < 8; ++u) {
            int co = cg * 8 + u;
            float s = lb[co];
#pragma unroll
            for (int t = 0; t < 27; ++t) s += nb[t] * lw[co * 27 + t];
            a[u] = s;
        }
        bf16x8 pk;
#pragma unroll
        for (int u = 0; u < 8; ++u) pk[u] = (short)f2b(a[u]);
        *(bf16x8*)(orow + cg * 8) = pk;
    }
}

// ---------------- MFMA implicit-GEMM 3x3 conv, Cin=64, N-group=64 ----------------
template<int MSUB>
__global__ __launch_bounds__(256, 2)
void k_mfconv(const unsigned short* __restrict__ in, const unsigned short* __restrict__ wp,
              const float* __restrict__ bias, const unsigned short* __restrict__ addsrc,
              unsigned short* __restrict__ out,
              int H, int W, int CoutReal, int outCs,
              long inImgStride, long outImgStride, int flags) {
    __shared__ uint4 ldsWv[4608];   // 73728 B
    const int tid = threadIdx.x;
    const uint4* wsrc = (const uint4*)(wp + (size_t)blockIdx.y * (9 * 64 * 64));
#pragma unroll
    for (int i = 0; i < 18; ++i) {
        int c = tid + i * 256;                 // 16B chunk id: [tap][n][g]
        uint4 v = wsrc[c];
        int tap = c >> 9, n = (c >> 3) & 63, g = c & 7;
        ldsWv[(tap * 64 + n) * 8 + (g ^ (n & 7))] = v;
    }
    __syncthreads();
    const bf16x8* ldsF = (const bf16x8*)ldsWv;

    const int lane = tid & 63, wv = tid >> 6;
    const int lr = lane & 15, lk = lane >> 4;
    const int nBase = blockIdx.y * 64;
    const unsigned short* inImg = in + (size_t)blockIdx.z * inImgStride;
    unsigned short* outImg = out + (size_t)blockIdx.z * outImgStride;
    const unsigned short* addImg = addsrc ? addsrc + (size_t)blockIdx.z * outImgStride : (const unsigned short*)0;

    const int mBase = blockIdx.x * (MSUB * 64) + wv * (MSUB * 16);
    int ys[MSUB], xs[MSUB];
#pragma unroll
    for (int i = 0; i < MSUB; ++i) {
        int m0 = mBase + i * 16;              // 16 consecutive m stay in one row (W%16==0)
        ys[i] = m0 / W; xs[i] = m0 - ys[i] * W;
    }

    f32x4 acc[MSUB][4];
#pragma unroll
    for (int j = 0; j < 4; ++j) {
        int n = nBase + j * 16 + lr;
        float bv = (n < CoutReal) ? bias[n] : 0.f;
#pragma unroll
        for (int i = 0; i < MSUB; ++i) acc[i][j] = (f32x4){bv, bv, bv, bv};
    }

#pragma unroll
    for (int ky = 0; ky < 3; ++ky) {
#pragma unroll
        for (int kx = 0; kx < 3; ++kx) {
            const int tap = ky * 3 + kx;
#pragma unroll
            for (int kk = 0; kk < 2; ++kk) {
                bf16x8 bf[4];
#pragma unroll
                for (int j = 0; j < 4; ++j) {
                    int n = j * 16 + lr;
                    bf[j] = ldsF[(tap * 64 + n) * 8 + (((kk << 2) | lk) ^ (n & 7))];
                }
                const int koff = kk * 32 + lk * 8;
#pragma unroll
                for (int i = 0; i < MSUB; ++i) {
                    int py = ys[i] + ky - 1;
                    int px = xs[i] + lr + kx - 1;
                    bf16x8 af = {0, 0, 0, 0, 0, 0, 0, 0};
                    if ((unsigned)py < (unsigned)H && (unsigned)px < (unsigned)W)
                        af = *(const bf16x8*)(inImg + ((size_t)py * W + px) * 64 + koff);
#pragma unroll
                    for (int j = 0; j < 4; ++j)
                        acc[i][j] = __builtin_amdgcn_mfma_f32_16x16x32_bf16(af, bf[j], acc[i][j], 0, 0, 0);
                }
            }
        }
    }

    const bool doRelu = flags & 1, doShuf = flags & 2, doAdd = flags & 4;
#pragma unroll
    for (int i = 0; i < MSUB; ++i) {
#pragma unroll
        for (int j = 0; j < 4; ++j) {
            int n = nBase + j * 16 + lr;
            f32x4 a = acc[i][j];
#pragma unroll
            for (int r = 0; r < 4; ++r) {
                float v = a[r];
                if (doRelu) v = fmaxf(v, 0.f);
                int y = ys[i], xcol = xs[i] + lk * 4 + r;   // D row = (lane>>4)*4 + r
                if (!doShuf) {
                    if (n < CoutReal) {
                        size_t o = ((size_t)y * W + xcol) * outCs + n;
                        if (doAdd) v += b2f(addImg[o]);
                        outImg[o] = f2b(v);
                    }
                } else {
                    int oc = n >> 2, si = (n >> 1) & 1, sj = n & 1;
                    size_t o = ((size_t)(2 * y + si) * (2 * W) + (2 * xcol + sj)) * 64 + oc;
                    outImg[o] = f2b(v);
                }
            }
        }
    }
}

// ---------------- zero the variance accumulator (BB*128 floats) ----------------
__global__ void k_zero(float* __restrict__ p) {
    p[threadIdx.x + blockIdx.x * 512] = 0.f;
}

// ---------------- variance partials: grid (36, BB), block 256 ----------------
// sums layout: [b][0:64]=sum, [b][64:128]=sum_sq
__global__ void k_varpart(const unsigned short* __restrict__ r1, float* __restrict__ sums) {
    int b = blockIdx.y, seg = blockIdx.x;
    int c = threadIdx.x & 63, q = threadIdx.x >> 6;
    const unsigned short* p0 = r1 + ((size_t)b * 9216 + seg * 256) * 64;
    float s = 0.f, s2 = 0.f;
#pragma unroll 4
    for (int i = 0; i < 64; ++i) {
        int p = q + i * 4;
        float t = b2f(p0[(size_t)p * 64 + c]);
        s += t; s2 += t * t;
    }
    __shared__ float sh[2][256];
    sh[0][threadIdx.x] = s; sh[1][threadIdx.x] = s2;
    __syncthreads();
    if (q == 0) {
#pragma unroll
        for (int k = 1; k < 4; ++k) { s += sh[0][c + 64 * k]; s2 += sh[1][c + 64 * k]; }
        atomicAdd(&sums[b * 128 + c], s);
        atomicAdd(&sums[b * 128 + 64 + c], s2);
    }
}

// ---------------- gates: variance finalize + subset-normalized sigmoid ----------------
__global__ void k_gate(const float* __restrict__ sums, float* __restrict__ g) {
    int b = blockIdx.x; int c = threadIdx.x;
    __shared__ float sv[64];
    __shared__ float stats[4];
    {
        const float n = 9216.f;
        float s = sums[b * 128 + c], s2 = sums[b * 128 + 64 + c];
        float mean = s / n;
        sv[c] = (s2 - n * mean * mean) / (n - 1.f);
    }
    __syncthreads();
    if (c == 0) {
        float mA = 0.f; for (int i = 16; i < 64; ++i) mA += sv[i]; mA /= 48.f;
        float sA = 0.f; for (int i = 16; i < 64; ++i) { float d = sv[i] - mA; sA += d * d; }
        sA = sqrtf(sA / 47.f);
        float mB = 0.f; for (int i = 0; i < 16; ++i) mB += sv[i]; mB /= 16.f;
        float sB = 0.f; for (int i = 0; i < 16; ++i) { float d = sv[i] - mB; sB += d * d; }
        sB = sqrtf(sB / 15.f);
        stats[0] = mA; stats[1] = sA; stats[2] = mB; stats[3] = sB;
    }
    __syncthreads();
    float gg;
    if (c >= 16) {
        float z = (sv[c] - stats[0]) / stats[1];
        gg = 0.5f / (1.f + expf(-z));
    } else {
        float z = (sv[c] - stats[2]) / stats[3];
        gg = 0.5f / (1.f + expf(-z)) + 0.5f;
    }
    g[b * 64 + c] = gg;
}

// ---------------- residual apply with channel permutation (bf16 NHWC) ----------------
__global__ void k_apply(unsigned short* __restrict__ t, const unsigned short* __restrict__ r1,
                        const float* __restrict__ g) {
    long total = (long)BB * 9216 * 64;
    long idx = blockIdx.x * 256L + threadIdx.x;
    if (idx >= total) return;
    int cn = (int)(idx & 63);
    long p = idx >> 6;                 // global pixel (b*9216 + pix)
    int b = (int)(p / 9216);
    int cs = (cn < 48) ? cn + 16 : cn - 48;
    float val = b2f(t[idx]) + g[b * 64 + cs] * b2f(r1[(p << 6) + cs]);
    t[idx] = f2b(val);
}

// ---------------- fused final (one image): out = base + pixel_conv + final conv ----------------
__global__ void k_final(const float* __restrict__ base, const unsigned short* __restrict__ f,
                        const unsigned short* __restrict__ ker, const float* __restrict__ wfin,
                        const float* __restrict__ bfin, float* __restrict__ out) {
    const int H = 384, W = 384;
    __shared__ float lw[3 * 64 * 9];
    for (int i = threadIdx.x; i < 1728; i += 256) lw[i] = wfin[i];
    __syncthreads();
    long idx = blockIdx.x * 256L + threadIdx.x;
    if (idx >= (long)H * W) return;
    int x = (int)(idx % W);
    int y = (int)(idx / W);

    float o2[3] = {bfin[0], bfin[1], bfin[2]};
#pragma unroll
    for (int ky = 0; ky < 3; ++ky)
#pragma unroll
        for (int kx = 0; kx < 3; ++kx) {
            int tap = ky * 3 + kx;
            int py = y + ky - 1, px = x + kx - 1;
            if ((unsigned)py >= (unsigned)H || (unsigned)px >= (unsigned)W) continue;
            const unsigned short* fp = f + ((size_t)py * W + px) * 64;
            for (int c8 = 0; c8 < 8; ++c8) {
                bf16x8 vv = *(const bf16x8*)(fp + c8 * 8);
#pragma unroll
                for (int u = 0; u < 8; ++u) {
                    float fv = b2f((unsigned short)vv[u]);
                    int ci = c8 * 8 + u;
                    o2[0] += fv * lw[(0 * 64 + ci) * 9 + tap];
                    o2[1] += fv * lw[(1 * 64 + ci) * 9 + tap];
                    o2[2] += fv * lw[(2 * 64 + ci) * 9 + tap];
                }
            }
        }

    // pixel_conv: gather from on-the-fly bilinear of base (top-left 385x385 corner quirk)
    float o1[3] = {0.f, 0.f, 0.f};
    const unsigned short* kp = ker + (size_t)idx * 32;
#pragma unroll
    for (int n9 = 0; n9 < 9; ++n9) {
        int dx = n9 / 3 - 1, dy = n9 % 3 - 1;   // torch meshgrid 'ij': dx outer, dy inner
        int p = y + dx, q = x + dy;
        float bv[3];
        if (p < 0 || q < 0) {
            bv[0] = bv[1] = bv[2] = 0.f;
        } else {
            float syf = 0.25f * p - 0.375f;
            float sxf = 0.25f * q - 0.375f;
            int iy0 = (int)floorf(syf); float fy = syf - iy0;
            int ix0 = (int)floorf(sxf); float fx = sxf - ix0;
            int iy1 = iy0 + 1, ix1 = ix0 + 1;
            iy0 = min(max(iy0, 0), H - 1); iy1 = min(max(iy1, 0), H - 1);
            ix0 = min(max(ix0, 0), W - 1); ix1 = min(max(ix1, 0), W - 1);
#pragma unroll
            for (int c = 0; c < 3; ++c) {
                const float* bp = base + (long)c * H * W;
                bv[c] = (1.f - fy) * ((1.f - fx) * bp[iy0 * W + ix0] + fx * bp[iy0 * W + ix1])
                      +        fy  * ((1.f - fx) * bp[iy1 * W + ix0] + fx * bp[iy1 * W + ix1]);
            }
        }
#pragma unroll
        for (int c = 0; c < 3; ++c)
            o1[c] += bv[c] * b2f(kp[n9 * 3 + c]);
    }

#pragma unroll
    for (int c = 0; c < 3; ++c) {
        long oi = ((long)c * H + y) * W + x;
        out[oi] = base[oi] + o2[c] + o1[c];
    }
}

// ==========================================================================
extern "C" void kernel_launch(void* const* d_in, const int* in_sizes, int n_in,
                              void* d_out, int out_size, void* d_ws, size_t ws_size,
                              hipStream_t stream) {
    const float* x       = (const float*)d_in[0];
    const float* w_first = (const float*)d_in[1];
    const float* b_first = (const float*)d_in[2];
    const float* w_blk1  = (const float*)d_in[3];
    const float* b_blk1  = (const float*)d_in[4];
    const float* w_blk2  = (const float*)d_in[5];
    const float* b_blk2  = (const float*)d_in[6];
    const float* w_after = (const float*)d_in[7];
    const float* b_after = (const float*)d_in[8];
    const float* w_up1   = (const float*)d_in[9];
    const float* b_up1   = (const float*)d_in[10];
    const float* w_up2   = (const float*)d_in[11];
    const float* b_up2   = (const float*)d_in[12];
    const float* w_fc1   = (const float*)d_in[13];
    const float* b_fc1   = (const float*)d_in[14];
    const float* w_fc2   = (const float*)d_in[15];
    const float* b_fc2   = (const float*)d_in[16];
    const float* w_kconv = (const float*)d_in[17];
    const float* b_kconv = (const float*)d_in[18];
    const float* w_final = (const float*)d_in[19];
    const float* b_final = (const float*)d_in[20];
    float* outp = (float*)d_out;
    (void)in_sizes; (void)n_in; (void)out_size; (void)ws_size;

    typedef unsigned short u16;
    char* ws = (char*)d_ws;
    size_t off = 0;
    auto alloc = [&](size_t bytes) {
        size_t o = off; off += (bytes + 255) & ~(size_t)255; return o;
    };
    const size_t SMB = (size_t)BB * 9216 * 64 * 2;       // 4.72 MB bf16 small map
    float* base = (float*)(ws + alloc((size_t)BB * 3 * 147456 * 4));   // 7.1 MB
    u16* h0   = (u16*)(ws + alloc(SMB));
    u16* t    = (u16*)(ws + alloc(SMB));
    u16* ta   = (u16*)(ws + alloc(SMB));
    u16* r1   = (u16*)(ws + alloc(SMB));
    float* sums = (float*)(ws + alloc(BB * 128 * 4));
    float* gbuf = (float*)(ws + alloc(BB * 64 * 4));
    u16* u1   = (u16*)(ws + alloc((size_t)BB * 36864 * 64 * 2));       // 18.9 MB
    u16* bigA = (u16*)(ws + alloc((size_t)147456 * 64 * 2));           // 18.9 MB (per-batch)
    u16* bigB = (u16*)(ws + alloc((size_t)147456 * 64 * 2));           // 18.9 MB
    u16* kerb = (u16*)(ws + alloc((size_t)147456 * 32 * 2));           // 9.4 MB
    // bf16 weights
    u16* wpB1 = (u16*)(ws + alloc((size_t)8 * 9 * 4096 * 2));
    u16* wpB2 = (u16*)(ws + alloc((size_t)8 * 9 * 4096 * 2));
    u16* wpAf = (u16*)(ws + alloc((size_t)9 * 4096 * 2));
    u16* wpU1 = (u16*)(ws + alloc((size_t)4 * 9 * 4096 * 2));
    u16* wpU2 = (u16*)(ws + alloc((size_t)4 * 9 * 4096 * 2));
    u16* wpF1 = (u16*)(ws + alloc((size_t)9 * 4096 * 2));
    u16* wpF2 = (u16*)(ws + alloc((size_t)9 * 4096 * 2));
    u16* wpKc = (u16*)(ws + alloc((size_t)9 * 4096 * 2));

    // ---- weight prep ----
    k_wprep<<<dim3(144, 8), 256, 0, stream>>>(w_blk1, wpB1, 64, 1);
    k_wprep<<<dim3(144, 8), 256, 0, stream>>>(w_blk2, wpB2, 64, 1);
    k_wprep<<<dim3(144, 1), 256, 0, stream>>>(w_after, wpAf, 64, 1);
    k_wprep<<<dim3(576, 1), 256, 0, stream>>>(w_up1, wpU1, 256, 4);
    k_wprep<<<dim3(576, 1), 256, 0, stream>>>(w_up2, wpU2, 256, 4);
    k_wprep<<<dim3(144, 1), 256, 0, stream>>>(w_fc1, wpF1, 64, 1);
    k_wprep<<<dim3(144, 1), 256, 0, stream>>>(w_fc2, wpF2, 64, 1);
    k_wprep<<<dim3(144, 1), 256, 0, stream>>>(w_kconv, wpKc, 27, 1);

    // ---- base + first ----
    k_bilinear4x<<<dim3(6912), 256, 0, stream>>>(x, base, BB, 3, HH, WW);
    k_first<<<dim3(36, 1, BB), 256, 0, stream>>>(x, w_first, b_first, h0);
    hipMemcpyAsync(t, h0, SMB, hipMemcpyDeviceToDevice, stream);

    const long smStride = 9216L * 64;
    // ---- MAM blocks ----
    for (int i = 0; i < 8; ++i) {
        const u16* wb1 = wpB1 + (size_t)i * 9 * 4096;
        const u16* wb2 = wpB2 + (size_t)i * 9 * 4096;
        k_mfconv<2><<<dim3(72, 1, BB), 256, 0, stream>>>(
            t, wb1, b_blk1 + (size_t)i * 64, nullptr, ta, 96, 96, 64, 64, smStride, smStride, 1);
        k_mfconv<2><<<dim3(72, 1, BB), 256, 0, stream>>>(
            ta, wb2, b_blk2 + (size_t)i * 64, nullptr, r1, 96, 96, 64, 64, smStride, smStride, 0);
        k_zero<<<dim3(1), 512, 0, stream>>>(sums);
        k_varpart<<<dim3(36, BB), 256, 0, stream>>>(r1, sums);
        k_gate<<<dim3(BB), 64, 0, stream>>>(sums, gbuf);
        k_apply<<<dim3(9216), 256, 0, stream>>>(t, r1, gbuf);
    }

    // ---- after conv (+h0 residual) ----
    k_mfconv<2><<<dim3(72, 1, BB), 256, 0, stream>>>(
        t, wpAf, b_after, h0, ta, 96, 96, 64, 64, smStride, smStride, 4);

    // ---- up1 (pixel_shuffle fused), full batch ----
    k_mfconv<4><<<dim3(36, 4, BB), 256, 0, stream>>>(
        ta, wpU1, b_up1, nullptr, u1, 96, 96, 256, 64, smStride, 36864L * 64, 2);

    // ---- per-batch 384^2 tail ----
    for (int b = 0; b < BB; ++b) {
        const u16* u1b = u1 + (size_t)b * 36864 * 64;
        const float* base_b = base + (size_t)b * 3 * 147456;
        float* out_b = outp + (size_t)b * 3 * 147456;
        // up2: 192^2 -> shuffle -> bigA [384^2][64]
        k_mfconv<4><<<dim3(144, 4, 1), 256, 0, stream>>>(
            u1b, wpU2, b_up2, nullptr, bigA, 192, 192, 256, 64, 0, 0, 2);
        // fc1: bigA -> bigB
        k_mfconv<4><<<dim3(576, 1, 1), 256, 0, stream>>>(
            bigA, wpF1, b_fc1, nullptr, bigB, 384, 384, 64, 64, 0, 0, 0);
        // fc2: bigB -> bigA (= f)
        k_mfconv<4><<<dim3(576, 1, 1), 256, 0, stream>>>(
            bigB, wpF2, b_fc2, nullptr, bigA, 384, 384, 64, 64, 0, 0, 0);
        // kconv: f -> kerb (27 of 32 ch)
        k_mfconv<4><<<dim3(576, 1, 1), 256, 0, stream>>>(
            bigA, wpKc, b_kconv, nullptr, kerb, 384, 384, 27, 32, 0, 0, 0);
        // final fuse
        k_final<<<dim3(576), 256, 0, stream>>>(base_b, bigA, kerb, w_final, b_final, out_b);
    }
}